// Round 6
// baseline (294.632 us; speedup 1.0000x reference)
//
#include <hip/hip_runtime.h>

// SSIM fused, round 11: kill the DS pipe load + 8 waves/SIMD (spill-proof).
//  - Round 10 result: spills GONE (WRITE 32 B, VGPR=56) but still 120 us.
//    Replay dispatches with ~zero HBM traffic ALSO take 120 us -> not
//    memory-bound; stall-bound: VALUBusy 30%, occupancy 2.7 waves/SIMD.
//    Per step each wave burned ~56 LDS-pipe cycles (4 ring DS ops + 20
//    epilogue bpermutes) + a serial ds_read->V->bperm->EPI chain, with too
//    few waves to hide it (935 CU-cyc/step measured vs ~460 of VALU work).
//  - Fixes (keeping the <=64-VGPR spill-proof design):
//      1. Drop the LDS pixel ring. Re-read row k-7 from GLOBAL (it was
//         read 7 steps ago by this same wave -> L2-resident; prefetched one
//         step ahead in a P/Q reg ping-pong exactly like the new-row A/B).
//         DS pipe now carries only the 20 epilogue bpermutes. No LDS block.
//      2. 8 waves/SIMD: live state ~55 regs fits a 64-reg budget on ANY
//         build (the bad build's 64-reg fallback is now the design point;
//         waves_per_eu(8,8) makes good builds match). Tiles resized to
//         feed it: TH=35 (NITER=41, warmup overhead 1.17x), grid
//         4 x 31 x 16 = 1984 blocks ~= 8 blocks/CU = 32 waves/CU.
//    Floors: VALU ~23 us, DS ~22 us, HBM ~49 us -> target 55-70 us.
// Geometry: 16 x 1 x 1080 x 1920 fp32; VALID 7x7 -> 16 x 1074 x 1914.

constexpr int W_IN = 1920, H_IN = 1080;
constexpr int WOUT = W_IN - 6;    // 1914
constexpr int HOUT = H_IN - 6;    // 1074
constexpr int NBATCH = 16;
constexpr int WCOLS = 122;        // productive cols per wave (61 lanes x 2)
constexpr int TW = 4 * WCOLS;     // 488 cols per block
constexpr int TH = 35;            // output rows per y-tile; NITER = 41
constexpr int NBX = 4, NBY = 31;  // 4*488>=1914(+pad), 31*35=1085>=1074
constexpr int NBLK = NBX * NBY * NBATCH;  // 1984 ~= 8 blocks/CU

constexpr float C1f = 6.5025f;    // (0.01*255)^2
constexpr float C2f = 58.5225f;   // (0.03*255)^2
constexpr float INV49 = 1.0f / 49.0f;

__device__ __forceinline__ float bperm(int addr, float v) {
  return __int_as_float(__builtin_amdgcn_ds_bpermute(addr, __float_as_int(v)));
}

__global__ __attribute__((amdgpu_flat_work_group_size(256, 256),
                          amdgpu_waves_per_eu(8, 8)))
void ssim_kernel(const float* __restrict__ img1, const float* __restrict__ img2,
                 double* __restrict__ partial) {
  __shared__ float wsum[4];

  const int t = threadIdx.x;
  const int lane = t & 63;
  const int xw = blockIdx.x * TW + (t >> 6) * WCOLS;  // wave col base
  const int y0 = blockIdx.y * TH;
  const size_t ib = (size_t)blockIdx.z * (size_t)(H_IN * W_IN);
  const float* __restrict__ p1 = img1 + ib;
  const float* __restrict__ p2 = img2 + ib;

  // gcol always even; clamp only hits halo-irrelevant lanes (see r6 notes).
  const int gcol = min(xw + 2 * lane, W_IN - 2);  // clamped, 8B-aligned
  const int up1 = ((lane + 1) & 63) << 2;         // bpermute byte addrs
  const int up2 = ((lane + 2) & 63) << 2;
  const int up3 = ((lane + 3) & 63) << 2;
  const bool lv = lane < 61;
  const bool m0 = lv && (xw + 2 * lane + 0 < WOUT);
  const bool m1 = lv && (xw + 2 * lane + 1 < WOUT);

  // running vertical sums: 5 quantities x 2 cols (the ONLY carried state)
  float V1_0 = 0.f, V1_1 = 0.f;   // sum a
  float V2_0 = 0.f, V2_1 = 0.f;   // sum b
  float V3_0 = 0.f, V3_1 = 0.f;   // sum a*a
  float V4_0 = 0.f, V4_1 = 0.f;   // sum b*b
  float V5_0 = 0.f, V5_1 = 0.f;   // sum a*b
  float accv = 0.f;

  // new-row prefetch ping-pong (A/B), old-row ping-pong (P/Q)
  float2 Aa = *(const float2*)(p1 + (size_t)y0 * W_IN + gcol);
  float2 Ab = *(const float2*)(p2 + (size_t)y0 * W_IN + gcol);
  float2 Ba, Bb, Pa, Pb, Qa, Qb;
  int gyn = y0 + 1;   // next NEW input row to load (block-uniform -> SALU)
  int gyo = y0 + 1;   // next OLD input row to prefetch
  int oy = y0;        // output row counter

#define EPI1(VA, VB, VAA, VBB, VAB, MASK)                                   \
  {                                                                         \
    const float mu1 = (VA) * INV49, mu2 = (VB) * INV49;                     \
    const float mu1s = mu1 * mu1, mu2s = mu2 * mu2, mu12 = mu1 * mu2;       \
    const float sg1 = fmaf((VAA), INV49, -mu1s);                            \
    const float sg2 = fmaf((VBB), INV49, -mu2s);                            \
    const float sg12 = fmaf((VAB), INV49, -mu12);                           \
    const float v1 = fmaf(2.f, sg12, C2f);                                  \
    const float v2 = sg1 + sg2 + C2f;                                       \
    const float num = fmaf(2.f, mu12, C1f) * v1;                            \
    const float den = (mu1s + mu2s + C1f) * v2;                             \
    const float ss = num * __builtin_amdgcn_rcpf(den);                      \
    accv += (MASK) ? ss : 0.f;                                              \
  }

  // horizontal 7-tap for quantity Q via pair sums + 4 bpermutes (r10 math)
#define HQ(Q)                                                               \
    const float s1_##Q = bperm(up1, H##Q);                                  \
    const float s2_##Q = bperm(up2, H##Q);                                  \
    const float s3_##Q = bperm(up3, H##Q);                                  \
    const float f3_##Q = bperm(up3, V##Q##_0);                              \
    const float sh_##Q = s1_##Q + s2_##Q;                                   \
    const float h0_##Q = (H##Q + sh_##Q) + f3_##Q;                          \
    const float h1_##Q = (V##Q##_1 + sh_##Q) + s3_##Q;

#define VUPD_ADD(CAa, CAb)                                                  \
    V1_0 += CAa.x;                   V1_1 += CAa.y;                         \
    V2_0 += CAb.x;                   V2_1 += CAb.y;                         \
    V3_0 = fmaf(CAa.x, CAa.x, V3_0); V3_1 = fmaf(CAa.y, CAa.y, V3_1);       \
    V4_0 = fmaf(CAb.x, CAb.x, V4_0); V4_1 = fmaf(CAb.y, CAb.y, V4_1);       \
    V5_0 = fmaf(CAa.x, CAb.x, V5_0); V5_1 = fmaf(CAa.y, CAb.y, V5_1);

#define VUPD_SUB(COa, COb)                                                  \
    V1_0 -= COa.x;                     V1_1 -= COa.y;                       \
    V2_0 -= COb.x;                     V2_1 -= COb.y;                       \
    V3_0 = fmaf(-COa.x, COa.x, V3_0);  V3_1 = fmaf(-COa.y, COa.y, V3_1);    \
    V4_0 = fmaf(-COb.x, COb.x, V4_0);  V4_1 = fmaf(-COb.y, COb.y, V4_1);    \
    V5_0 = fmaf(-COa.x, COb.x, V5_0);  V5_1 = fmaf(-COa.y, COb.y, V5_1);

#define DO_EPI_BLOCK                                                        \
    if (oy < HOUT) {                                                        \
      const float H1 = V1_0 + V1_1;                                         \
      const float H2 = V2_0 + V2_1;                                         \
      const float H3 = V3_0 + V3_1;                                         \
      const float H4 = V4_0 + V4_1;                                         \
      const float H5 = V5_0 + V5_1;                                         \
      HQ(1) HQ(2) HQ(3) HQ(4) HQ(5)                                         \
      EPI1(h0_1, h0_2, h0_3, h0_4, h0_5, m0)                                \
      EPI1(h1_1, h1_2, h1_3, h1_4, h1_5, m1)                                \
    }                                                                       \
    ++oy;

  // warm-up step: add new row only (rows y0..y0+6 have no row to retire)
#define STEPW(CAa, CAb, NAa, NAb, DO_EPI)                                   \
  {                                                                         \
    NAa = *(const float2*)(p1 + (size_t)gyn * W_IN + gcol);                 \
    NAb = *(const float2*)(p2 + (size_t)gyn * W_IN + gcol);                 \
    gyn = min(gyn + 1, H_IN - 1);                                           \
    VUPD_ADD(CAa, CAb)                                                      \
    if (DO_EPI) { DO_EPI_BLOCK }                                            \
  }

  // main step: prefetch next new row + next old row; add CA, retire CO.
  // Old row k-7 is re-read from global: it was fetched 7 steps ago by this
  // same wave -> L2-resident; clamped with the SAME min() as when added.
#define STEPM(CAa, CAb, NAa, NAb, COa, COb, NOa, NOb)                       \
  {                                                                         \
    NAa = *(const float2*)(p1 + (size_t)gyn * W_IN + gcol);                 \
    NAb = *(const float2*)(p2 + (size_t)gyn * W_IN + gcol);                 \
    gyn = min(gyn + 1, H_IN - 1);                                           \
    {                                                                       \
      const int yo = min(gyo, H_IN - 1);                                    \
      NOa = *(const float2*)(p1 + (size_t)yo * W_IN + gcol);                \
      NOb = *(const float2*)(p2 + (size_t)yo * W_IN + gcol);                \
      ++gyo;                                                                \
    }                                                                       \
    VUPD_ADD(CAa, CAb)                                                      \
    VUPD_SUB(COa, COb)                                                      \
    DO_EPI_BLOCK                                                            \
  }

  // warm-up: rows y0..y0+6 (row k in A if k-y0 even); step 6 emits row y0
  STEPW(Aa, Ab, Ba, Bb, false)
  STEPW(Ba, Bb, Aa, Ab, false)
  STEPW(Aa, Ab, Ba, Bb, false)
  STEPW(Ba, Bb, Aa, Ab, false)
  STEPW(Aa, Ab, Ba, Bb, false)
  STEPW(Ba, Bb, Aa, Ab, false)
  STEPW(Aa, Ab, Ba, Bb, true)
  // old-row prologue: row y0 -> P (consumed by the first main step)
  Pa = *(const float2*)(p1 + (size_t)y0 * W_IN + gcol);
  Pb = *(const float2*)(p2 + (size_t)y0 * W_IN + gcol);
  // 17 pairs: steps 7..40 (new row in B for odd steps, A for even)
  for (int gp = 0; gp < 17; ++gp) {
    STEPM(Ba, Bb, Aa, Ab, Pa, Pb, Qa, Qb)
    STEPM(Aa, Ab, Ba, Bb, Qa, Qb, Pa, Pb)
  }
#undef STEPM
#undef STEPW
#undef DO_EPI_BLOCK
#undef VUPD_SUB
#undef VUPD_ADD
#undef HQ
#undef EPI1

  // block reduction: 64-wide shuffle -> LDS -> one double per block
#pragma unroll
  for (int off = 32; off > 0; off >>= 1) accv += __shfl_down(accv, off);
  if ((t & 63) == 0) wsum[t >> 6] = accv;
  __syncthreads();
  if (t == 0) {
    const int bid = blockIdx.x + NBX * (blockIdx.y + NBY * blockIdx.z);
    partial[bid] = (double)wsum[0] + (double)wsum[1] +
                   (double)wsum[2] + (double)wsum[3];
  }
}

__global__ __launch_bounds__(256)
void finalize_kernel(const double* __restrict__ partial,
                     float* __restrict__ out) {
  const int tid = threadIdx.x;
  double s = 0.0;
  for (int i = tid; i < NBLK; i += 256) s += partial[i];
#pragma unroll
  for (int off = 32; off > 0; off >>= 1) s += __shfl_down(s, off);
  __shared__ double ws[4];
  if ((tid & 63) == 0) ws[tid >> 6] = s;
  __syncthreads();
  if (tid == 0) {
    const double tot = ws[0] + ws[1] + ws[2] + ws[3];
    out[0] = (float)(tot / ((double)NBATCH * (double)HOUT * (double)WOUT));
  }
}

extern "C" void kernel_launch(void* const* d_in, const int* in_sizes, int n_in,
                              void* d_out, int out_size, void* d_ws, size_t ws_size,
                              hipStream_t stream) {
  const float* img1 = (const float*)d_in[0];
  const float* img2 = (const float*)d_in[1];
  // d_in[2] is the uniform 1/49 window -- baked into INV49.
  double* partial = (double*)d_ws;  // NBLK doubles, every slot written
  dim3 grid(NBX, NBY, NBATCH);      // 4 x 31 x 16 = 1984 blocks
  hipLaunchKernelGGL(ssim_kernel, grid, dim3(256), 0, stream, img1, img2,
                     partial);
  hipLaunchKernelGGL(finalize_kernel, dim3(1), dim3(256), 0, stream, partial,
                     (float*)d_out);
}